// Round 1
// baseline (55313.947 us; speedup 1.0000x reference)
//
#include <hip/hip_runtime.h>
#include <cstdint>
#include <cstddef>

#define T_STEPS 512
#define BATCH   1024
#define IN_DIM  178
#define NH1     64
#define NG1     256      // 4*H1
#define NH2     32
#define NG2     128      // 4*H2
#define TCHUNK  4
#define NCHUNK  (T_STEPS / TCHUNK)
#define BPW     4        // batch elements per workgroup
#define XROW    (BATCH * IN_DIM)

__device__ __forceinline__ float sigmoidf_(float v) {
    return 1.0f / (1.0f + __expf(-v));
}
__device__ __forceinline__ float tanhf_(float v) {
    // tanh(x) = 1 - 2/(exp(2x)+1); saturates correctly for large |x|
    return 1.0f - 2.0f / (__expf(2.0f * v) + 1.0f);
}

struct __align__(16) SM {
    float xproj[TCHUNK][BPW][NG1];  // 16 KB  input-proj results (bias included)
    float w1s[NG1 * 16];            // 16 KB  staged w_ih1 k-block (XOR-swizzled)
    float red[16][NG1];             // 16 KB  partial sums [kq*4+b][g]
    float h1s[BPW][NH1];            // 1 KB
    float h2s[BPW][NH2];            // 0.5 KB
    float b1s[NG1];                 // b_ih1+b_hh1
    float b2s[NG2];                 // b_ih2+b_hh2
    float wds[2 * NH2];             // dense weight
    float bds[4];                   // dense bias (padded)
};

extern "C" __global__ __launch_bounds__(1024) void lstm_fused_kernel(
    const float* __restrict__ x,
    const float* __restrict__ w_ih1, const float* __restrict__ w_hh1,
    const float* __restrict__ b_ih1, const float* __restrict__ b_hh1,
    const float* __restrict__ w_ih2, const float* __restrict__ w_hh2,
    const float* __restrict__ b_ih2, const float* __restrict__ b_hh2,
    const float* __restrict__ w_dense, const float* __restrict__ b_dense,
    float* __restrict__ out)
{
    __shared__ SM sm;
    const int tid = threadIdx.x;
    const int b0  = blockIdx.x * BPW;

    // ---------------- one-time init ----------------
    if (tid < NG1) sm.b1s[tid] = b_ih1[tid] + b_hh1[tid];
    else if (tid < NG1 + NG2) { int i = tid - NG1; sm.b2s[i] = b_ih2[i] + b_hh2[i]; }
    else if (tid < NG1 + NG2 + 2 * NH2) { int i = tid - NG1 - NG2; sm.wds[i] = w_dense[i]; }
    else if (tid < NG1 + NG2 + 2 * NH2 + 2) { int i = tid - NG1 - NG2 - 2 * NH2; sm.bds[i] = b_dense[i]; }
    if (tid < BPW * NH1) ((float*)sm.h1s)[tid] = 0.0f;
    if (tid < BPW * NH2) ((float*)sm.h2s)[tid] = 0.0f;

    // L1 recurrent weights: thread (g1 = tid&255, kq1 = tid>>8) owns w_hh1[g1][kq1*16 .. +16)
    const int g1  = tid & 255;
    const int kq1 = tid >> 8;
    float wr1[16];
    #pragma unroll
    for (int j = 0; j < 16; ++j) wr1[j] = w_hh1[g1 * NH1 + kq1 * 16 + j];

    // L2 weights (concat [w_ih2 | w_hh2] along k: 96 cols), threads < 512:
    // thread (g2 = tid&127, kq2 = tid>>7) owns cols kq2*24 .. +24
    const int g2  = tid & 127;
    const int kq2 = tid >> 7;
    float wr2[24];
    if (tid < 512) {
        #pragma unroll
        for (int j = 0; j < 24; ++j) {
            int kk = kq2 * 24 + j;
            wr2[j] = (kk < NH1) ? w_ih2[g2 * NH1 + kk] : w_hh2[g2 * NH2 + (kk - NH1)];
        }
    }

    float c1 = 0.0f;  // cell state, owned by tid<256 as (b=tid>>6, h=tid&63)
    float c2 = 0.0f;  // cell state, owned by tid<128 as (b=tid>>5, h=tid&31)

    // staging / in-proj index helpers
    const int sg    = tid >> 2;                    // staging row (0..255)
    const int sc4   = tid & 3;                     // staging col-block
    const int swz_s = ((sc4 ^ ((sg >> 1) & 3)) << 2);
    const int bi_   = tid >> 8;                    // in-proj batch slot (0..3)
    const int swz_r = (g1 >> 1) & 3;               // reader xor key

    __syncthreads();

    for (int chunk = 0; chunk < NCHUNK; ++chunk) {
        const int t0 = chunk * TCHUNK;

        // ================= input projection for this chunk =================
        float acc[TCHUNK] = {0.f, 0.f, 0.f, 0.f};
        const float* xb = x + ((size_t)t0 * BATCH + (size_t)(b0 + bi_)) * IN_DIM;

        for (int kb = 0; kb < 12; ++kb) {           // 12 k-blocks of 16 (covers 178, zero-padded)
            __syncthreads();
            // stage w_ih1[:, kb*16 .. +16) into LDS, swizzled; zero-pad k>=178
            #pragma unroll
            for (int j = 0; j < 4; ++j) {
                int k = kb * 16 + sc4 * 4 + j;
                sm.w1s[sg * 16 + swz_s + j] = (k < IN_DIM) ? w_ih1[sg * IN_DIM + k] : 0.0f;
            }
            __syncthreads();

            #pragma unroll
            for (int c4 = 0; c4 < 4; ++c4) {
                const float4 wv = *(const float4*)&sm.w1s[g1 * 16 + ((c4 ^ swz_r) << 2)];
                const int k = kb * 16 + c4 * 4;
                if (kb < 11) {
                    #pragma unroll
                    for (int tt = 0; tt < TCHUNK; ++tt) {
                        const float2* xp = (const float2*)(xb + (size_t)tt * XROW + k);
                        float2 xa = xp[0];
                        float2 xc = xp[1];
                        acc[tt] += xa.x * wv.x + xa.y * wv.y + xc.x * wv.z + xc.y * wv.w;
                    }
                } else if (k < IN_DIM) {            // tail block: k = 176..179, guard loads
                    #pragma unroll
                    for (int tt = 0; tt < TCHUNK; ++tt) {
                        const float* xp = xb + (size_t)tt * XROW;
                        float s = 0.0f;
                        if (k + 0 < IN_DIM) s += xp[k + 0] * wv.x;
                        if (k + 1 < IN_DIM) s += xp[k + 1] * wv.y;
                        if (k + 2 < IN_DIM) s += xp[k + 2] * wv.z;
                        if (k + 3 < IN_DIM) s += xp[k + 3] * wv.w;
                        acc[tt] += s;
                    }
                }
            }
        }
        {
            float b1v = sm.b1s[g1];
            #pragma unroll
            for (int tt = 0; tt < TCHUNK; ++tt)
                sm.xproj[tt][bi_][g1] = acc[tt] + b1v;
        }
        __syncthreads();

        // ================= TCHUNK recurrent steps =================
        for (int tt = 0; tt < TCHUNK; ++tt) {
            const int t = t0 + tt;

            // ---- Phase A: L1 recurrent partials (all 1024 threads) ----
            #pragma unroll
            for (int b = 0; b < BPW; ++b) {
                const float4* hp = (const float4*)&sm.h1s[b][kq1 * 16];
                float p = 0.0f;
                #pragma unroll
                for (int j4 = 0; j4 < 4; ++j4) {
                    float4 hv = hp[j4];
                    p += hv.x * wr1[j4 * 4 + 0] + hv.y * wr1[j4 * 4 + 1]
                       + hv.z * wr1[j4 * 4 + 2] + hv.w * wr1[j4 * 4 + 3];
                }
                sm.red[kq1 * 4 + b][g1] = p;
            }
            __syncthreads();

            // ---- Phase C: L1 combine + pointwise (tid < 256) ----
            if (tid < 256) {
                const int b = tid >> 6, h = tid & 63;
                float gi = sm.xproj[tt][b][h]
                         + sm.red[b][h] + sm.red[4 + b][h] + sm.red[8 + b][h] + sm.red[12 + b][h];
                float gf = sm.xproj[tt][b][64 + h]
                         + sm.red[b][64 + h] + sm.red[4 + b][64 + h] + sm.red[8 + b][64 + h] + sm.red[12 + b][64 + h];
                float gg = sm.xproj[tt][b][128 + h]
                         + sm.red[b][128 + h] + sm.red[4 + b][128 + h] + sm.red[8 + b][128 + h] + sm.red[12 + b][128 + h];
                float go = sm.xproj[tt][b][192 + h]
                         + sm.red[b][192 + h] + sm.red[4 + b][192 + h] + sm.red[8 + b][192 + h] + sm.red[12 + b][192 + h];
                float iv = sigmoidf_(gi);
                float fv = sigmoidf_(gf);
                float gv = tanhf_(gg);
                float ov = sigmoidf_(go);
                c1 = fv * c1 + iv * gv;
                sm.h1s[b][h] = ov * tanhf_(c1);
            }
            __syncthreads();

            // ---- Phase B: L2 partials (tid < 512) ∥ Phase D: dense for step t-1 ----
            if (tid < 512) {
                #pragma unroll
                for (int b = 0; b < BPW; ++b) {
                    float p = 0.0f;
                    #pragma unroll
                    for (int j4 = 0; j4 < 6; ++j4) {
                        int kk = kq2 * 24 + j4 * 4;
                        float4 v;
                        if (kk < NH1) {
                            float4 hv = *(const float4*)&sm.h1s[b][kk];
                            v.x = fmaxf(hv.x, 0.f); v.y = fmaxf(hv.y, 0.f);
                            v.z = fmaxf(hv.z, 0.f); v.w = fmaxf(hv.w, 0.f);
                        } else {
                            v = *(const float4*)&sm.h2s[b][kk - NH1];
                        }
                        p += v.x * wr2[j4 * 4 + 0] + v.y * wr2[j4 * 4 + 1]
                           + v.z * wr2[j4 * 4 + 2] + v.w * wr2[j4 * 4 + 3];
                    }
                    sm.red[kq2 * 4 + b][g2] = p;
                }
            } else if (tid < 520) {
                if (t > 0) {   // dense head for step t-1 (h2s still holds h2(t-1))
                    const int b = (tid >> 1) & 3, o = tid & 1;
                    float a = sm.bds[o];
                    #pragma unroll
                    for (int k = 0; k < NH2; ++k)
                        a += sigmoidf_(sm.h2s[b][k]) * sm.wds[o * NH2 + k];
                    out[(size_t)(t - 1) * (2 * BATCH) + (size_t)(b0 + b) * 2 + o] = sigmoidf_(a);
                }
            }
            __syncthreads();

            // ---- Phase C2: L2 combine + pointwise (tid < 128) ----
            if (tid < 128) {
                const int b = tid >> 5, h = tid & 31;
                float gi = sm.b2s[h]
                         + sm.red[b][h] + sm.red[4 + b][h] + sm.red[8 + b][h] + sm.red[12 + b][h];
                float gf = sm.b2s[32 + h]
                         + sm.red[b][32 + h] + sm.red[4 + b][32 + h] + sm.red[8 + b][32 + h] + sm.red[12 + b][32 + h];
                float gg = sm.b2s[64 + h]
                         + sm.red[b][64 + h] + sm.red[4 + b][64 + h] + sm.red[8 + b][64 + h] + sm.red[12 + b][64 + h];
                float go = sm.b2s[96 + h]
                         + sm.red[b][96 + h] + sm.red[4 + b][96 + h] + sm.red[8 + b][96 + h] + sm.red[12 + b][96 + h];
                float iv = sigmoidf_(gi);
                float fv = sigmoidf_(gf);
                float gv = tanhf_(gg);
                float ov = sigmoidf_(go);
                c2 = fv * c2 + iv * gv;
                sm.h2s[b][h] = ov * tanhf_(c2);
            }
            __syncthreads();
        }
    }

    // final dense head for t = 511
    if (tid < 8) {
        const int b = tid >> 1, o = tid & 1;
        float a = sm.bds[o];
        #pragma unroll
        for (int k = 0; k < NH2; ++k)
            a += sigmoidf_(sm.h2s[b][k]) * sm.wds[o * NH2 + k];
        out[(size_t)511 * (2 * BATCH) + (size_t)(b0 + b) * 2 + o] = sigmoidf_(a);
    }
}

extern "C" void kernel_launch(void* const* d_in, const int* in_sizes, int n_in,
                              void* d_out, int out_size, void* d_ws, size_t ws_size,
                              hipStream_t stream) {
    const float* x       = (const float*)d_in[0];
    const float* w_ih1   = (const float*)d_in[1];
    const float* w_hh1   = (const float*)d_in[2];
    const float* b_ih1   = (const float*)d_in[3];
    const float* b_hh1   = (const float*)d_in[4];
    const float* w_ih2   = (const float*)d_in[5];
    const float* w_hh2   = (const float*)d_in[6];
    const float* b_ih2   = (const float*)d_in[7];
    const float* b_hh2   = (const float*)d_in[8];
    const float* w_dense = (const float*)d_in[9];
    const float* b_dense = (const float*)d_in[10];
    float* out = (float*)d_out;

    dim3 grid(BATCH / BPW / 1);   // 256 workgroups (one per CU)
    dim3 block(1024);
    hipLaunchKernelGGL(lstm_fused_kernel, dim3(256), block, 0, stream,
                       x, w_ih1, w_hh1, b_ih1, b_hh1,
                       w_ih2, w_hh2, b_ih2, b_hh2,
                       w_dense, b_dense, out);
    (void)grid; (void)in_sizes; (void)n_in; (void)out_size; (void)d_ws; (void)ws_size;
}

// Round 2
// 8916.930 us; speedup vs baseline: 6.2033x; 6.2033x over previous
//
#include <hip/hip_runtime.h>
#include <cstdint>
#include <cstddef>

#define T_STEPS 512
#define BATCH   1024
#define IN_DIM  178
#define NH1     64
#define NG1     256      // 4*H1
#define NH2     32
#define NG2     128      // 4*H2
#define TCHUNK  4
#define NCHUNK  (T_STEPS / TCHUNK)
#define BPW     4        // batch elements per workgroup
#define XROW    (BATCH * IN_DIM)

__device__ __forceinline__ float sigmoidf_(float v) {
    return 1.0f / (1.0f + __expf(-v));
}
__device__ __forceinline__ float tanhf_(float v) {
    return 1.0f - 2.0f / (__expf(2.0f * v) + 1.0f);
}

struct __align__(16) SM {
    float xproj[TCHUNK][BPW][NG1];  // 16 KB  input-proj results (bias included)
    float w1sA[NG1 * 16];           // 16 KB  staging buffer A (swizzled 16B slots)
    union {
        float red[16][NG1];         // 16 KB  recurrent partial sums [kq*4+b][g]
        float w1sB[NG1 * 16];       //        staging buffer B (aliased; red unused in in-proj)
    } u;
    float h1s[BPW][NH1];            // 1 KB
    float h2s[BPW][NH2];            // 0.5 KB
    float b1s[NG1];
    float b2s[NG2];
    float wds[2 * NH2];
    float bds[4];
};

// Load one staged quad of w_ih1 (row sg, cols k0..k0+3) into registers. Zero-pad k>=178.
__device__ __forceinline__ float4 stage_load(const float* __restrict__ w_ih1,
                                             int sg, int k0, bool tail) {
    float4 v;
    if (!tail) {
        const float2* p = (const float2*)(w_ih1 + (size_t)sg * IN_DIM + k0);
        float2 a = p[0], b = p[1];
        v.x = a.x; v.y = a.y; v.z = b.x; v.w = b.y;
    } else {
        v.x = (k0 + 0 < IN_DIM) ? w_ih1[(size_t)sg * IN_DIM + k0 + 0] : 0.0f;
        v.y = (k0 + 1 < IN_DIM) ? w_ih1[(size_t)sg * IN_DIM + k0 + 1] : 0.0f;
        v.z = (k0 + 2 < IN_DIM) ? w_ih1[(size_t)sg * IN_DIM + k0 + 2] : 0.0f;
        v.w = (k0 + 3 < IN_DIM) ? w_ih1[(size_t)sg * IN_DIM + k0 + 3] : 0.0f;
    }
    return v;
}

// Single b128 write to the swizzled slot: 16-lane groups cover 8 distinct 16B slots
// -> conflict-free (the round-1 scalar-store version was an 8-way conflict).
__device__ __forceinline__ void stage_write(float* buf, int sg, int sslot, float4 v) {
    *(float4*)&buf[sg * 16 + sslot] = v;
}

// FMA over one 16-col k-block: b128 swizzled LDS read of w, wave-uniform x loads.
__device__ __forceinline__ void inproj_compute(const float* __restrict__ xb,
                                               const float* buf, int kb,
                                               int g1, int swz_r,
                                               float acc[TCHUNK], bool tail) {
    #pragma unroll
    for (int c4 = 0; c4 < 4; ++c4) {
        const float4 wv = *(const float4*)&buf[g1 * 16 + (((c4) ^ swz_r) << 2)];
        const int k = kb * 16 + c4 * 4;
        if (!tail) {
            #pragma unroll
            for (int tt = 0; tt < TCHUNK; ++tt) {
                const float2* xp = (const float2*)(xb + (size_t)tt * XROW + k);
                float2 xa = xp[0];
                float2 xc = xp[1];
                acc[tt] += xa.x * wv.x + xa.y * wv.y + xc.x * wv.z + xc.y * wv.w;
            }
        } else if (k < IN_DIM) {
            #pragma unroll
            for (int tt = 0; tt < TCHUNK; ++tt) {
                const float* xp = xb + (size_t)tt * XROW;
                float s = 0.0f;
                if (k + 0 < IN_DIM) s += xp[k + 0] * wv.x;
                if (k + 1 < IN_DIM) s += xp[k + 1] * wv.y;
                acc[tt] += s;   // k+2/k+3 have wv.z=wv.w=0 from padding
            }
        }
    }
}

// block = 1024 threads (16 waves), exactly 1 block/CU (grid 256).
// __launch_bounds__(1024, 4): 4 waves/EU -> VGPR cap 128 (round 1's default
// targeted 64 VGPRs and spilled wr1/wr2 to scratch: 103 GB WRITE_SIZE, 55 ms).
extern "C" __global__ __launch_bounds__(1024, 4) void lstm_fused_kernel(
    const float* __restrict__ x,
    const float* __restrict__ w_ih1, const float* __restrict__ w_hh1,
    const float* __restrict__ b_ih1, const float* __restrict__ b_hh1,
    const float* __restrict__ w_ih2, const float* __restrict__ w_hh2,
    const float* __restrict__ b_ih2, const float* __restrict__ b_hh2,
    const float* __restrict__ w_dense, const float* __restrict__ b_dense,
    float* __restrict__ out)
{
    __shared__ SM sm;
    const int tid = threadIdx.x;
    const int b0  = blockIdx.x * BPW;

    // ---------------- one-time init ----------------
    if (tid < NG1) sm.b1s[tid] = b_ih1[tid] + b_hh1[tid];
    else if (tid < NG1 + NG2) { int i = tid - NG1; sm.b2s[i] = b_ih2[i] + b_hh2[i]; }
    else if (tid < NG1 + NG2 + 2 * NH2) { int i = tid - NG1 - NG2; sm.wds[i] = w_dense[i]; }
    else if (tid < NG1 + NG2 + 2 * NH2 + 2) { int i = tid - NG1 - NG2 - 2 * NH2; sm.bds[i] = b_dense[i]; }
    if (tid < BPW * NH1) ((float*)sm.h1s)[tid] = 0.0f;
    if (tid < BPW * NH2) ((float*)sm.h2s)[tid] = 0.0f;

    // L1 recurrent weights: thread (g1 = tid&255, kq1 = tid>>8) owns w_hh1[g1][kq1*16 .. +16)
    const int g1  = tid & 255;
    const int kq1 = tid >> 8;
    float wr1[16];
    #pragma unroll
    for (int j = 0; j < 16; ++j) wr1[j] = w_hh1[g1 * NH1 + kq1 * 16 + j];

    // L2 weights (concat [w_ih2 | w_hh2] along k: 96 cols), threads < 512
    const int g2  = tid & 127;
    const int kq2 = tid >> 7;
    float wr2[24];
    if (tid < 512) {
        #pragma unroll
        for (int j = 0; j < 24; ++j) {
            int kk = kq2 * 24 + j;
            wr2[j] = (kk < NH1) ? w_ih2[g2 * NH1 + kk] : w_hh2[g2 * NH2 + (kk - NH1)];
        }
    }

    float c1 = 0.0f;  // tid<256: (b=tid>>6, h=tid&63)
    float c2 = 0.0f;  // tid<128: (b=tid>>5, h=tid&31)

    // staging / in-proj index helpers
    const int sg    = tid >> 2;                      // staging row (0..255)
    const int sc4   = tid & 3;                       // logical 16B slot
    const int sslot = ((sc4 ^ ((sg >> 1) & 3)) << 2);// swizzled float offset
    const int bi_   = tid >> 8;                      // in-proj batch slot (0..3)
    const int swz_r = (g1 >> 1) & 3;                 // reader xor key

    __syncthreads();

    for (int chunk = 0; chunk < NCHUNK; ++chunk) {
        const int t0 = chunk * TCHUNK;

        // ================= input projection for this chunk =================
        float acc[TCHUNK] = {0.f, 0.f, 0.f, 0.f};
        const float* xb = x + ((size_t)t0 * BATCH + (size_t)(b0 + bi_)) * IN_DIM;

        // prologue: stage kb=0 into A
        {
            float4 v0 = stage_load(w_ih1, sg, 0 * 16 + sc4 * 4, false);
            stage_write(sm.w1sA, sg, sslot, v0);
        }
        __syncthreads();

        // double-buffered: compute A/B alternately, 1 barrier per k-block
        #pragma unroll 1
        for (int kb2 = 0; kb2 < 6; ++kb2) {
            const int kbA = 2 * kb2;
            const int kbB = 2 * kb2 + 1;
            const bool tailB = (kbB == 11);

            float4 vB = stage_load(w_ih1, sg, kbB * 16 + sc4 * 4, tailB);
            inproj_compute(xb, sm.w1sA, kbA, g1, swz_r, acc, false);
            stage_write(sm.u.w1sB, sg, sslot, vB);
            __syncthreads();

            const bool haveA2 = (kb2 < 5);
            float4 vA2;
            if (haveA2) vA2 = stage_load(w_ih1, sg, (kbB + 1) * 16 + sc4 * 4, false);
            inproj_compute(xb, sm.u.w1sB, kbB, g1, swz_r, acc, tailB);
            if (haveA2) stage_write(sm.w1sA, sg, sslot, vA2);
            __syncthreads();
        }

        {
            float b1v = sm.b1s[g1];
            #pragma unroll
            for (int tt = 0; tt < TCHUNK; ++tt)
                sm.xproj[tt][bi_][g1] = acc[tt] + b1v;
        }
        __syncthreads();   // also protects w1sB(=red) before Phase A writes red

        // ================= TCHUNK recurrent steps =================
        for (int tt = 0; tt < TCHUNK; ++tt) {
            const int t = t0 + tt;

            // ---- Phase A: L1 recurrent partials (all 1024 threads) ----
            #pragma unroll
            for (int b = 0; b < BPW; ++b) {
                const float4* hp = (const float4*)&sm.h1s[b][kq1 * 16];  // wave-uniform -> broadcast
                float p = 0.0f;
                #pragma unroll
                for (int j4 = 0; j4 < 4; ++j4) {
                    float4 hv = hp[j4];
                    p += hv.x * wr1[j4 * 4 + 0] + hv.y * wr1[j4 * 4 + 1]
                       + hv.z * wr1[j4 * 4 + 2] + hv.w * wr1[j4 * 4 + 3];
                }
                sm.u.red[kq1 * 4 + b][g1] = p;
            }
            __syncthreads();

            // ---- Phase C: L1 combine + pointwise (tid < 256) ----
            if (tid < 256) {
                const int b = tid >> 6, h = tid & 63;
                float gi = sm.xproj[tt][b][h]
                         + sm.u.red[b][h] + sm.u.red[4 + b][h] + sm.u.red[8 + b][h] + sm.u.red[12 + b][h];
                float gf = sm.xproj[tt][b][64 + h]
                         + sm.u.red[b][64 + h] + sm.u.red[4 + b][64 + h] + sm.u.red[8 + b][64 + h] + sm.u.red[12 + b][64 + h];
                float gg = sm.xproj[tt][b][128 + h]
                         + sm.u.red[b][128 + h] + sm.u.red[4 + b][128 + h] + sm.u.red[8 + b][128 + h] + sm.u.red[12 + b][128 + h];
                float go = sm.xproj[tt][b][192 + h]
                         + sm.u.red[b][192 + h] + sm.u.red[4 + b][192 + h] + sm.u.red[8 + b][192 + h] + sm.u.red[12 + b][192 + h];
                float iv = sigmoidf_(gi);
                float fv = sigmoidf_(gf);
                float gv = tanhf_(gg);
                float ov = sigmoidf_(go);
                c1 = fv * c1 + iv * gv;
                sm.h1s[b][h] = ov * tanhf_(c1);
            }
            __syncthreads();

            // ---- Phase B: L2 partials (tid < 512) ∥ Phase D: dense for t-1 ----
            if (tid < 512) {
                #pragma unroll
                for (int b = 0; b < BPW; ++b) {
                    float p = 0.0f;
                    #pragma unroll
                    for (int j4 = 0; j4 < 6; ++j4) {
                        int kk = kq2 * 24 + j4 * 4;
                        float4 v;
                        if (kk < NH1) {
                            float4 hv = *(const float4*)&sm.h1s[b][kk];   // wave-uniform
                            v.x = fmaxf(hv.x, 0.f); v.y = fmaxf(hv.y, 0.f);
                            v.z = fmaxf(hv.z, 0.f); v.w = fmaxf(hv.w, 0.f);
                        } else {
                            v = *(const float4*)&sm.h2s[b][kk - NH1];     // wave-uniform
                        }
                        p += v.x * wr2[j4 * 4 + 0] + v.y * wr2[j4 * 4 + 1]
                           + v.z * wr2[j4 * 4 + 2] + v.w * wr2[j4 * 4 + 3];
                    }
                    sm.u.red[kq2 * 4 + b][g2] = p;
                }
            } else if (tid < 520) {
                if (t > 0) {   // dense head for step t-1 (h2s still holds h2(t-1))
                    const int b = (tid >> 1) & 3, o = tid & 1;
                    float a = sm.bds[o];
                    #pragma unroll
                    for (int k = 0; k < NH2; ++k)
                        a += sigmoidf_(sm.h2s[b][k]) * sm.wds[o * NH2 + k];
                    out[(size_t)(t - 1) * (2 * BATCH) + (size_t)(b0 + b) * 2 + o] = sigmoidf_(a);
                }
            }
            __syncthreads();

            // ---- Phase C2: L2 combine + pointwise (tid < 128) ----
            if (tid < 128) {
                const int b = tid >> 5, h = tid & 31;
                float gi = sm.b2s[h]
                         + sm.u.red[b][h] + sm.u.red[4 + b][h] + sm.u.red[8 + b][h] + sm.u.red[12 + b][h];
                float gf = sm.b2s[32 + h]
                         + sm.u.red[b][32 + h] + sm.u.red[4 + b][32 + h] + sm.u.red[8 + b][32 + h] + sm.u.red[12 + b][32 + h];
                float gg = sm.b2s[64 + h]
                         + sm.u.red[b][64 + h] + sm.u.red[4 + b][64 + h] + sm.u.red[8 + b][64 + h] + sm.u.red[12 + b][64 + h];
                float go = sm.b2s[96 + h]
                         + sm.u.red[b][96 + h] + sm.u.red[4 + b][96 + h] + sm.u.red[8 + b][96 + h] + sm.u.red[12 + b][96 + h];
                float iv = sigmoidf_(gi);
                float fv = sigmoidf_(gf);
                float gv = tanhf_(gg);
                float ov = sigmoidf_(go);
                c2 = fv * c2 + iv * gv;
                sm.h2s[b][h] = ov * tanhf_(c2);
            }
            __syncthreads();
        }
    }

    // final dense head for t = 511
    if (tid < 8) {
        const int b = tid >> 1, o = tid & 1;
        float a = sm.bds[o];
        #pragma unroll
        for (int k = 0; k < NH2; ++k)
            a += sigmoidf_(sm.h2s[b][k]) * sm.wds[o * NH2 + k];
        out[(size_t)511 * (2 * BATCH) + (size_t)(b0 + b) * 2 + o] = sigmoidf_(a);
    }
}

extern "C" void kernel_launch(void* const* d_in, const int* in_sizes, int n_in,
                              void* d_out, int out_size, void* d_ws, size_t ws_size,
                              hipStream_t stream) {
    const float* x       = (const float*)d_in[0];
    const float* w_ih1   = (const float*)d_in[1];
    const float* w_hh1   = (const float*)d_in[2];
    const float* b_ih1   = (const float*)d_in[3];
    const float* b_hh1   = (const float*)d_in[4];
    const float* w_ih2   = (const float*)d_in[5];
    const float* w_hh2   = (const float*)d_in[6];
    const float* b_ih2   = (const float*)d_in[7];
    const float* b_hh2   = (const float*)d_in[8];
    const float* w_dense = (const float*)d_in[9];
    const float* b_dense = (const float*)d_in[10];
    float* out = (float*)d_out;

    hipLaunchKernelGGL(lstm_fused_kernel, dim3(256), dim3(1024), 0, stream,
                       x, w_ih1, w_hh1, b_ih1, b_hh1,
                       w_ih2, w_hh2, b_ih2, b_hh2,
                       w_dense, b_dense, out);
    (void)in_sizes; (void)n_in; (void)out_size; (void)d_ws; (void)ws_size;
}

// Round 3
// 8815.342 us; speedup vs baseline: 6.2747x; 1.0115x over previous
//
#include <hip/hip_runtime.h>
#include <cstdint>
#include <cstddef>

#define T_STEPS 512
#define BATCH   1024
#define IN_DIM  178
#define NH1     64
#define NG1     256      // 4*H1
#define NH2     32
#define NG2     128      // 4*H2
#define TCHUNK  4
#define NCHUNK  (T_STEPS / TCHUNK)
#define BPW     4        // batch elements per workgroup
#define XROW    (BATCH * IN_DIM)

__device__ __forceinline__ float sigmoidf_(float v) {
    return 1.0f / (1.0f + __expf(-v));
}
__device__ __forceinline__ float tanhf_(float v) {
    return 1.0f - 2.0f / (__expf(2.0f * v) + 1.0f);
}

struct __align__(16) SM {
    float xproj[TCHUNK][BPW][NG1];  // 16 KB  input-proj results (bias included)
    float w1sA[NG1 * 16];           // 16 KB  staging buffer A (swizzled 16B slots)
    union {
        float red[16][NG1];         // 16 KB  recurrent partial sums [kq*4+b][g]
        float w1sB[NG1 * 16];       //        staging buffer B (aliased; red unused in in-proj)
    } u;
    float h1s[BPW][NH1];            // 1 KB
    float h2s[BPW][NH2];            // 0.5 KB
    float b1s[NG1];
    float b2s[NG2];
    float wds[2 * NH2];
    float bds[4];
};

// Load one staged quad of w_ih1 (row sg, cols k0..k0+3) into registers. Zero-pad k>=178.
__device__ __forceinline__ float4 stage_load(const float* __restrict__ w_ih1,
                                             int sg, int k0, bool tail) {
    float4 v;
    if (!tail) {
        const float2* p = (const float2*)(w_ih1 + (size_t)sg * IN_DIM + k0);
        float2 a = p[0], b = p[1];
        v.x = a.x; v.y = a.y; v.z = b.x; v.w = b.y;
    } else {
        v.x = (k0 + 0 < IN_DIM) ? w_ih1[(size_t)sg * IN_DIM + k0 + 0] : 0.0f;
        v.y = (k0 + 1 < IN_DIM) ? w_ih1[(size_t)sg * IN_DIM + k0 + 1] : 0.0f;
        v.z = (k0 + 2 < IN_DIM) ? w_ih1[(size_t)sg * IN_DIM + k0 + 2] : 0.0f;
        v.w = (k0 + 3 < IN_DIM) ? w_ih1[(size_t)sg * IN_DIM + k0 + 3] : 0.0f;
    }
    return v;
}

__device__ __forceinline__ void stage_write(float* buf, int sg, int sslot, float4 v) {
    *(float4*)&buf[sg * 16 + sslot] = v;
}

// FMA over one 16-col k-block: b128 swizzled LDS read of w, wave-uniform x loads.
__device__ __forceinline__ void inproj_compute(const float* __restrict__ xb,
                                               const float* buf, int kb,
                                               int g1, int swz_r,
                                               float acc[TCHUNK], bool tail) {
    #pragma unroll
    for (int c4 = 0; c4 < 4; ++c4) {
        const float4 wv = *(const float4*)&buf[g1 * 16 + (((c4) ^ swz_r) << 2)];
        const int k = kb * 16 + c4 * 4;
        if (!tail) {
            #pragma unroll
            for (int tt = 0; tt < TCHUNK; ++tt) {
                const float2* xp = (const float2*)(xb + (size_t)tt * XROW + k);
                float2 xa = xp[0];
                float2 xc = xp[1];
                acc[tt] += xa.x * wv.x + xa.y * wv.y + xc.x * wv.z + xc.y * wv.w;
            }
        } else if (k < IN_DIM) {
            #pragma unroll
            for (int tt = 0; tt < TCHUNK; ++tt) {
                const float* xp = xb + (size_t)tt * XROW;
                float s = 0.0f;
                if (k + 0 < IN_DIM) s += xp[k + 0] * wv.x;
                if (k + 1 < IN_DIM) s += xp[k + 1] * wv.y;
                acc[tt] += s;   // k+2/k+3 have wv.z=wv.w=0 from padding
            }
        }
    }
}

// block = 1024 threads (16 waves), exactly 1 block/CU (grid 256).
// amdgpu_waves_per_eu(4,4): round 2 showed __launch_bounds__(1024,4) only sets a
// MINIMUM; the compiler targeted the LDS-implied 8 waves/EU -> 64-VGPR cap ->
// wr1/wr2 spilled (4.6 GB scratch WRITE_SIZE). Pinning max=4 raises the cap to 128.
extern "C" __global__
__attribute__((amdgpu_flat_work_group_size(1024, 1024)))
__attribute__((amdgpu_waves_per_eu(4, 4)))
void lstm_fused_kernel(
    const float* __restrict__ x,
    const float* __restrict__ w_ih1, const float* __restrict__ w_hh1,
    const float* __restrict__ b_ih1, const float* __restrict__ b_hh1,
    const float* __restrict__ w_ih2, const float* __restrict__ w_hh2,
    const float* __restrict__ b_ih2, const float* __restrict__ b_hh2,
    const float* __restrict__ w_dense, const float* __restrict__ b_dense,
    float* __restrict__ out)
{
    __shared__ SM sm;
    const int tid = threadIdx.x;
    const int b0  = blockIdx.x * BPW;

    // ---------------- one-time init ----------------
    if (tid < NG1) sm.b1s[tid] = b_ih1[tid] + b_hh1[tid];
    else if (tid < NG1 + NG2) { int i = tid - NG1; sm.b2s[i] = b_ih2[i] + b_hh2[i]; }
    else if (tid < NG1 + NG2 + 2 * NH2) { int i = tid - NG1 - NG2; sm.wds[i] = w_dense[i]; }
    else if (tid < NG1 + NG2 + 2 * NH2 + 2) { int i = tid - NG1 - NG2 - 2 * NH2; sm.bds[i] = b_dense[i]; }
    if (tid < BPW * NH1) ((float*)sm.h1s)[tid] = 0.0f;
    if (tid < BPW * NH2) ((float*)sm.h2s)[tid] = 0.0f;

    // L1 recurrent weights: thread (g1 = tid&255, kq1 = tid>>8) owns w_hh1[g1][kq1*16 .. +16)
    const int g1  = tid & 255;
    const int kq1 = tid >> 8;
    float wr1[16];
    #pragma unroll
    for (int j = 0; j < 16; ++j) wr1[j] = w_hh1[g1 * NH1 + kq1 * 16 + j];

    // L2 weights (concat [w_ih2 | w_hh2] along k: 96 cols), threads < 512
    const int g2  = tid & 127;
    const int kq2 = tid >> 7;
    float wr2[24];
    if (tid < 512) {
        #pragma unroll
        for (int j = 0; j < 24; ++j) {
            int kk = kq2 * 24 + j;
            wr2[j] = (kk < NH1) ? w_ih2[g2 * NH1 + kk] : w_hh2[g2 * NH2 + (kk - NH1)];
        }
    }

    float c1 = 0.0f;  // tid<256: (b=tid>>6, h=tid&63)
    float c2 = 0.0f;  // tid<128: (b=tid>>5, h=tid&31)

    // staging / in-proj index helpers
    const int sg    = tid >> 2;                      // staging row (0..255)
    const int sc4   = tid & 3;                       // logical 16B slot
    const int sslot = ((sc4 ^ ((sg >> 1) & 3)) << 2);// swizzled float offset
    const int bi_   = tid >> 8;                      // in-proj batch slot (0..3)
    const int swz_r = (g1 >> 1) & 3;                 // reader xor key

    __syncthreads();

    for (int chunk = 0; chunk < NCHUNK; ++chunk) {
        const int t0 = chunk * TCHUNK;

        // ================= input projection for this chunk =================
        float acc[TCHUNK] = {0.f, 0.f, 0.f, 0.f};
        const float* xb = x + ((size_t)t0 * BATCH + (size_t)(b0 + bi_)) * IN_DIM;

        // prologue: stage kb=0 into A
        {
            float4 v0 = stage_load(w_ih1, sg, 0 * 16 + sc4 * 4, false);
            stage_write(sm.w1sA, sg, sslot, v0);
        }
        __syncthreads();

        // double-buffered: compute A/B alternately, 1 barrier per k-block
        #pragma unroll 1
        for (int kb2 = 0; kb2 < 6; ++kb2) {
            const int kbA = 2 * kb2;
            const int kbB = 2 * kb2 + 1;
            const bool tailB = (kbB == 11);

            float4 vB = stage_load(w_ih1, sg, kbB * 16 + sc4 * 4, tailB);
            inproj_compute(xb, sm.w1sA, kbA, g1, swz_r, acc, false);
            stage_write(sm.u.w1sB, sg, sslot, vB);
            __syncthreads();

            const bool haveA2 = (kb2 < 5);
            float4 vA2;
            if (haveA2) vA2 = stage_load(w_ih1, sg, (kbB + 1) * 16 + sc4 * 4, false);
            inproj_compute(xb, sm.u.w1sB, kbB, g1, swz_r, acc, tailB);
            if (haveA2) stage_write(sm.w1sA, sg, sslot, vA2);
            __syncthreads();
        }

        {
            float b1v = sm.b1s[g1];
            #pragma unroll
            for (int tt = 0; tt < TCHUNK; ++tt)
                sm.xproj[tt][bi_][g1] = acc[tt] + b1v;
        }
        __syncthreads();   // also protects w1sB(=red) before Phase A writes red

        // ================= TCHUNK recurrent steps =================
        for (int tt = 0; tt < TCHUNK; ++tt) {
            const int t = t0 + tt;

            // ---- Phase A: L1 recurrent partials (all 1024 threads) ----
            #pragma unroll
            for (int b = 0; b < BPW; ++b) {
                const float4* hp = (const float4*)&sm.h1s[b][kq1 * 16];  // wave-uniform -> broadcast
                float p = 0.0f;
                #pragma unroll
                for (int j4 = 0; j4 < 4; ++j4) {
                    float4 hv = hp[j4];
                    p += hv.x * wr1[j4 * 4 + 0] + hv.y * wr1[j4 * 4 + 1]
                       + hv.z * wr1[j4 * 4 + 2] + hv.w * wr1[j4 * 4 + 3];
                }
                sm.u.red[kq1 * 4 + b][g1] = p;
            }
            __syncthreads();

            // ---- Phase C: L1 combine + pointwise (tid < 256) ----
            if (tid < 256) {
                const int b = tid >> 6, h = tid & 63;
                float gi = sm.xproj[tt][b][h]
                         + sm.u.red[b][h] + sm.u.red[4 + b][h] + sm.u.red[8 + b][h] + sm.u.red[12 + b][h];
                float gf = sm.xproj[tt][b][64 + h]
                         + sm.u.red[b][64 + h] + sm.u.red[4 + b][64 + h] + sm.u.red[8 + b][64 + h] + sm.u.red[12 + b][64 + h];
                float gg = sm.xproj[tt][b][128 + h]
                         + sm.u.red[b][128 + h] + sm.u.red[4 + b][128 + h] + sm.u.red[8 + b][128 + h] + sm.u.red[12 + b][128 + h];
                float go = sm.xproj[tt][b][192 + h]
                         + sm.u.red[b][192 + h] + sm.u.red[4 + b][192 + h] + sm.u.red[8 + b][192 + h] + sm.u.red[12 + b][192 + h];
                float iv = sigmoidf_(gi);
                float fv = sigmoidf_(gf);
                float gv = tanhf_(gg);
                float ov = sigmoidf_(go);
                c1 = fv * c1 + iv * gv;
                sm.h1s[b][h] = ov * tanhf_(c1);
            }
            __syncthreads();

            // ---- Phase B: L2 partials (tid < 512) ∥ Phase D: dense for t-1 ----
            if (tid < 512) {
                #pragma unroll
                for (int b = 0; b < BPW; ++b) {
                    float p = 0.0f;
                    #pragma unroll
                    for (int j4 = 0; j4 < 6; ++j4) {
                        int kk = kq2 * 24 + j4 * 4;
                        float4 v;
                        if (kk < NH1) {
                            float4 hv = *(const float4*)&sm.h1s[b][kk];   // wave-uniform
                            v.x = fmaxf(hv.x, 0.f); v.y = fmaxf(hv.y, 0.f);
                            v.z = fmaxf(hv.z, 0.f); v.w = fmaxf(hv.w, 0.f);
                        } else {
                            v = *(const float4*)&sm.h2s[b][kk - NH1];     // wave-uniform
                        }
                        p += v.x * wr2[j4 * 4 + 0] + v.y * wr2[j4 * 4 + 1]
                           + v.z * wr2[j4 * 4 + 2] + v.w * wr2[j4 * 4 + 3];
                    }
                    sm.u.red[kq2 * 4 + b][g2] = p;
                }
            } else if (tid < 520) {
                if (t > 0) {   // dense head for step t-1 (h2s still holds h2(t-1))
                    const int b = (tid >> 1) & 3, o = tid & 1;
                    float a = sm.bds[o];
                    #pragma unroll
                    for (int k = 0; k < NH2; ++k)
                        a += sigmoidf_(sm.h2s[b][k]) * sm.wds[o * NH2 + k];
                    out[(size_t)(t - 1) * (2 * BATCH) + (size_t)(b0 + b) * 2 + o] = sigmoidf_(a);
                }
            }
            __syncthreads();

            // ---- Phase C2: L2 combine + pointwise (tid < 128) ----
            if (tid < 128) {
                const int b = tid >> 5, h = tid & 31;
                float gi = sm.b2s[h]
                         + sm.u.red[b][h] + sm.u.red[4 + b][h] + sm.u.red[8 + b][h] + sm.u.red[12 + b][h];
                float gf = sm.b2s[32 + h]
                         + sm.u.red[b][32 + h] + sm.u.red[4 + b][32 + h] + sm.u.red[8 + b][32 + h] + sm.u.red[12 + b][32 + h];
                float gg = sm.b2s[64 + h]
                         + sm.u.red[b][64 + h] + sm.u.red[4 + b][64 + h] + sm.u.red[8 + b][64 + h] + sm.u.red[12 + b][64 + h];
                float go = sm.b2s[96 + h]
                         + sm.u.red[b][96 + h] + sm.u.red[4 + b][96 + h] + sm.u.red[8 + b][96 + h] + sm.u.red[12 + b][96 + h];
                float iv = sigmoidf_(gi);
                float fv = sigmoidf_(gf);
                float gv = tanhf_(gg);
                float ov = sigmoidf_(go);
                c2 = fv * c2 + iv * gv;
                sm.h2s[b][h] = ov * tanhf_(c2);
            }
            __syncthreads();
        }
    }

    // final dense head for t = 511
    if (tid < 8) {
        const int b = tid >> 1, o = tid & 1;
        float a = sm.bds[o];
        #pragma unroll
        for (int k = 0; k < NH2; ++k)
            a += sigmoidf_(sm.h2s[b][k]) * sm.wds[o * NH2 + k];
        out[(size_t)511 * (2 * BATCH) + (size_t)(b0 + b) * 2 + o] = sigmoidf_(a);
    }
}

extern "C" void kernel_launch(void* const* d_in, const int* in_sizes, int n_in,
                              void* d_out, int out_size, void* d_ws, size_t ws_size,
                              hipStream_t stream) {
    const float* x       = (const float*)d_in[0];
    const float* w_ih1   = (const float*)d_in[1];
    const float* w_hh1   = (const float*)d_in[2];
    const float* b_ih1   = (const float*)d_in[3];
    const float* b_hh1   = (const float*)d_in[4];
    const float* w_ih2   = (const float*)d_in[5];
    const float* w_hh2   = (const float*)d_in[6];
    const float* b_ih2   = (const float*)d_in[7];
    const float* b_hh2   = (const float*)d_in[8];
    const float* w_dense = (const float*)d_in[9];
    const float* b_dense = (const float*)d_in[10];
    float* out = (float*)d_out;

    hipLaunchKernelGGL(lstm_fused_kernel, dim3(256), dim3(1024), 0, stream,
                       x, w_ih1, w_hh1, b_ih1, b_hh1,
                       w_ih2, w_hh2, b_ih2, b_hh2,
                       w_dense, b_dense, out);
    (void)in_sizes; (void)n_in; (void)out_size; (void)d_ws; (void)ws_size;
}